// Round 23
// baseline (600.519 us; speedup 1.0000x reference)
//
#include <hip/hip_runtime.h>

// Cvxpy_81174881894666: batched dual ascent (R23: 1-barrier, redundant sigmoid)
//   per batch b: 100 iters of
//     z = a^T lam;  y = sigmoid(-(c+z));  g = a y + b;  lam = max(lam+0.05 g, 0)
//   out: y = sigmoid(-(c + a^T lam_final)) [2048,256] f32, status int32 zeros.
//
// R21/R22 post-mortem: VALUBusy(gfx94x formula) is 2x-inflated; asm kernels
// are ~50% stall-bound (766 cy/wave-iter vs 392 issue). Stalls = 2 barriers
// + 3 LDS round-trips/iter, only 2 blocks/CU to hide. R23: each lane gathers
// all 8 waves' zp for ITS 4 cols (8 x ds_read_b128 + 28 adds) and computes
// 4 sigmoids redundantly -> y4 born in registers, y-broadcast + barrier-2
// deleted. zp double-buffered (1024B rows, toggle = v_xor 0x2000): with one
// barrier, write(k+2,buf0) is ordered after all read(k,buf0). P1/P3 blocks
// verbatim from R21 (PASS), reduce tree verbatim from R22 (PASS, map
// myrow=(l>>2)&15).

#define BB 2048
#define MM 128
#define NN 256

__global__ __launch_bounds__(512, 2) void cvx_dual_ascent(
    const float* __restrict__ A,
    const float* __restrict__ Bv,
    const float* __restrict__ C,
    float* __restrict__ out)
{
    const int bi  = blockIdx.x;
    const int tid = threadIdx.x;
    const int w   = tid >> 6;          // wave 0..7 -> rows [16w,16w+16)
    const int l   = tid & 63;
    const int myrow = (l >> 2) & 15;   // row owned after reduce (R22 map)

    __shared__ float zp2_s[2][8][256]; // z partials, dbuf; row stride 1024B
    __shared__ float lam_s[8][16];     // per-wave lambda (wave-private)

    const float* Ab = A + (size_t)bi * (MM * NN);
    unsigned long long a0  = (unsigned long long)(Ab + (16*w + 0)  * NN + 4*l);
    unsigned long long a4  = (unsigned long long)(Ab + (16*w + 4)  * NN + 4*l);
    unsigned long long a8  = (unsigned long long)(Ab + (16*w + 8)  * NN + 4*l);
    unsigned long long a12 = (unsigned long long)(Ab + (16*w + 12) * NN + 4*l);
    unsigned lamrd = (unsigned)(size_t)&lam_s[w][0];
    unsigned zpw   = (unsigned)(size_t)&zp2_s[0][w][4*l];   // toggled by 0x2000
    unsigned zprd  = (unsigned)(size_t)&zp2_s[0][0][4*l];   // +w2*1024 imm
    unsigned lamw  = (unsigned)(size_t)&lam_s[w][myrow];
    unsigned long long outa = (unsigned long long)(out + (size_t)bi * NN + 4*l);
    const float4 c4 = *reinterpret_cast<const float4*>(&C[bi * NN + 4*l]);
    float c0 = c4.x, c1 = c4.y, c2 = c4.z, c3 = c4.w;
    float sbv = 0.05f * Bv[bi * MM + 16*w + myrow];
    float lam = 0.f;
    float wvf = (float)0;  // unused float; keep w in int vgpr below
    int   wvv = w;
    int   cnt = 100;
    (void)wvf;

    if (tid < 128) lam_s[tid >> 4][tid & 15] = 0.f;
    __syncthreads();

    asm volatile(
        // ---- A tile -> v[36:99]; gate SGPR s78 = wave id ----
        "v_readfirstlane_b32 s78, %[wvv]\n\t"
        "global_load_dwordx4 v[36:39], %[a0], off\n\t"
        "global_load_dwordx4 v[40:43], %[a0], off offset:1024\n\t"
        "global_load_dwordx4 v[44:47], %[a0], off offset:2048\n\t"
        "global_load_dwordx4 v[48:51], %[a0], off offset:3072\n\t"
        "global_load_dwordx4 v[52:55], %[a4], off\n\t"
        "global_load_dwordx4 v[56:59], %[a4], off offset:1024\n\t"
        "global_load_dwordx4 v[60:63], %[a4], off offset:2048\n\t"
        "global_load_dwordx4 v[64:67], %[a4], off offset:3072\n\t"
        "global_load_dwordx4 v[68:71], %[a8], off\n\t"
        "global_load_dwordx4 v[72:75], %[a8], off offset:1024\n\t"
        "global_load_dwordx4 v[76:79], %[a8], off offset:2048\n\t"
        "global_load_dwordx4 v[80:83], %[a8], off offset:3072\n\t"
        "global_load_dwordx4 v[84:87], %[a12], off\n\t"
        "global_load_dwordx4 v[88:91], %[a12], off offset:1024\n\t"
        "global_load_dwordx4 v[92:95], %[a12], off offset:2048\n\t"
        "global_load_dwordx4 v[96:99], %[a12], off offset:3072\n\t"
        "s_waitcnt vmcnt(0)\n\t"
        ".LTOP%=:\n\t"
        // ---- P1 (R21 verbatim): lam v100-115, acc v116-119 ----
        "ds_read_b128 v[100:103], %[lamrd]\n\t"
        "ds_read_b128 v[104:107], %[lamrd] offset:16\n\t"
        "ds_read_b128 v[108:111], %[lamrd] offset:32\n\t"
        "ds_read_b128 v[112:115], %[lamrd] offset:48\n\t"
        "s_waitcnt lgkmcnt(0)\n\t"
        "v_mul_f32 v116, v36, v100\n\t"
        "v_mul_f32 v117, v37, v100\n\t"
        "v_mul_f32 v118, v38, v100\n\t"
        "v_mul_f32 v119, v39, v100\n\t"
        "v_fmac_f32 v116, v40, v101\n\t"
        "v_fmac_f32 v117, v41, v101\n\t"
        "v_fmac_f32 v118, v42, v101\n\t"
        "v_fmac_f32 v119, v43, v101\n\t"
        "v_fmac_f32 v116, v44, v102\n\t"
        "v_fmac_f32 v117, v45, v102\n\t"
        "v_fmac_f32 v118, v46, v102\n\t"
        "v_fmac_f32 v119, v47, v102\n\t"
        "v_fmac_f32 v116, v48, v103\n\t"
        "v_fmac_f32 v117, v49, v103\n\t"
        "v_fmac_f32 v118, v50, v103\n\t"
        "v_fmac_f32 v119, v51, v103\n\t"
        "v_fmac_f32 v116, v52, v104\n\t"
        "v_fmac_f32 v117, v53, v104\n\t"
        "v_fmac_f32 v118, v54, v104\n\t"
        "v_fmac_f32 v119, v55, v104\n\t"
        "v_fmac_f32 v116, v56, v105\n\t"
        "v_fmac_f32 v117, v57, v105\n\t"
        "v_fmac_f32 v118, v58, v105\n\t"
        "v_fmac_f32 v119, v59, v105\n\t"
        "v_fmac_f32 v116, v60, v106\n\t"
        "v_fmac_f32 v117, v61, v106\n\t"
        "v_fmac_f32 v118, v62, v106\n\t"
        "v_fmac_f32 v119, v63, v106\n\t"
        "v_fmac_f32 v116, v64, v107\n\t"
        "v_fmac_f32 v117, v65, v107\n\t"
        "v_fmac_f32 v118, v66, v107\n\t"
        "v_fmac_f32 v119, v67, v107\n\t"
        "v_fmac_f32 v116, v68, v108\n\t"
        "v_fmac_f32 v117, v69, v108\n\t"
        "v_fmac_f32 v118, v70, v108\n\t"
        "v_fmac_f32 v119, v71, v108\n\t"
        "v_fmac_f32 v116, v72, v109\n\t"
        "v_fmac_f32 v117, v73, v109\n\t"
        "v_fmac_f32 v118, v74, v109\n\t"
        "v_fmac_f32 v119, v75, v109\n\t"
        "v_fmac_f32 v116, v76, v110\n\t"
        "v_fmac_f32 v117, v77, v110\n\t"
        "v_fmac_f32 v118, v78, v110\n\t"
        "v_fmac_f32 v119, v79, v110\n\t"
        "v_fmac_f32 v116, v80, v111\n\t"
        "v_fmac_f32 v117, v81, v111\n\t"
        "v_fmac_f32 v118, v82, v111\n\t"
        "v_fmac_f32 v119, v83, v111\n\t"
        "v_fmac_f32 v116, v84, v112\n\t"
        "v_fmac_f32 v117, v85, v112\n\t"
        "v_fmac_f32 v118, v86, v112\n\t"
        "v_fmac_f32 v119, v87, v112\n\t"
        "v_fmac_f32 v116, v88, v113\n\t"
        "v_fmac_f32 v117, v89, v113\n\t"
        "v_fmac_f32 v118, v90, v113\n\t"
        "v_fmac_f32 v119, v91, v113\n\t"
        "v_fmac_f32 v116, v92, v114\n\t"
        "v_fmac_f32 v117, v93, v114\n\t"
        "v_fmac_f32 v118, v94, v114\n\t"
        "v_fmac_f32 v119, v95, v114\n\t"
        "v_fmac_f32 v116, v96, v115\n\t"
        "v_fmac_f32 v117, v97, v115\n\t"
        "v_fmac_f32 v118, v98, v115\n\t"
        "v_fmac_f32 v119, v99, v115\n\t"
        "ds_write_b128 %[zpw], v[116:119]\n\t"
        "s_waitcnt lgkmcnt(0)\n\t"
        "s_barrier\n\t"
        // ---- P2: gather zp of all 8 waves for MY 4 cols; sum; 4 sigmoids ----
        "ds_read_b128 v[100:103], %[zprd]\n\t"
        "ds_read_b128 v[104:107], %[zprd] offset:1024\n\t"
        "ds_read_b128 v[108:111], %[zprd] offset:2048\n\t"
        "ds_read_b128 v[112:115], %[zprd] offset:3072\n\t"
        "ds_read_b128 v[120:123], %[zprd] offset:4096\n\t"
        "ds_read_b128 v[124:127], %[zprd] offset:5120\n\t"
        "s_waitcnt lgkmcnt(0)\n\t"
        "v_add_f32 v100, v100, v104\n\t"
        "v_add_f32 v101, v101, v105\n\t"
        "v_add_f32 v102, v102, v106\n\t"
        "v_add_f32 v103, v103, v107\n\t"
        "v_add_f32 v108, v108, v112\n\t"
        "v_add_f32 v109, v109, v113\n\t"
        "v_add_f32 v110, v110, v114\n\t"
        "v_add_f32 v111, v111, v115\n\t"
        "v_add_f32 v120, v120, v124\n\t"
        "v_add_f32 v121, v121, v125\n\t"
        "v_add_f32 v122, v122, v126\n\t"
        "v_add_f32 v123, v123, v127\n\t"
        "v_add_f32 v100, v100, v108\n\t"
        "v_add_f32 v101, v101, v109\n\t"
        "v_add_f32 v102, v102, v110\n\t"
        "v_add_f32 v103, v103, v111\n\t"
        "ds_read_b128 v[104:107], %[zprd] offset:6144\n\t"
        "ds_read_b128 v[108:111], %[zprd] offset:7168\n\t"
        "v_add_f32 v100, v100, v120\n\t"
        "v_add_f32 v101, v101, v121\n\t"
        "v_add_f32 v102, v102, v122\n\t"
        "v_add_f32 v103, v103, v123\n\t"
        "s_waitcnt lgkmcnt(0)\n\t"
        "v_add_f32 v104, v104, v108\n\t"
        "v_add_f32 v105, v105, v109\n\t"
        "v_add_f32 v106, v106, v110\n\t"
        "v_add_f32 v107, v107, v111\n\t"
        "v_add_f32 v100, v100, v104\n\t"
        "v_add_f32 v101, v101, v105\n\t"
        "v_add_f32 v102, v102, v106\n\t"
        "v_add_f32 v103, v103, v107\n\t"
        // toggle zp buffers for next iter
        "v_xor_b32 %[zpw], 0x2000, %[zpw]\n\t"
        "v_xor_b32 %[zprd], 0x2000, %[zprd]\n\t"
        // sigmoid x4: y = rcp(1 + 2^((c+z)*log2e))
        "v_add_f32 v116, %[c0], v100\n\t"
        "v_add_f32 v117, %[c1], v101\n\t"
        "v_add_f32 v118, %[c2], v102\n\t"
        "v_add_f32 v119, %[c3], v103\n\t"
        "v_mul_f32 v116, %[l2e], v116\n\t"
        "v_mul_f32 v117, %[l2e], v117\n\t"
        "v_mul_f32 v118, %[l2e], v118\n\t"
        "v_mul_f32 v119, %[l2e], v119\n\t"
        "v_exp_f32 v116, v116\n\t"
        "v_exp_f32 v117, v117\n\t"
        "v_exp_f32 v118, v118\n\t"
        "v_exp_f32 v119, v119\n\t"
        "s_nop 1\n\t"
        "v_add_f32 v116, 1.0, v116\n\t"
        "v_add_f32 v117, 1.0, v117\n\t"
        "v_add_f32 v118, 1.0, v118\n\t"
        "v_add_f32 v119, 1.0, v119\n\t"
        "v_rcp_f32 v116, v116\n\t"
        "v_rcp_f32 v117, v117\n\t"
        "v_rcp_f32 v118, v118\n\t"
        "v_rcp_f32 v119, v119\n\t"
        "s_nop 1\n\t"
        "s_cmp_eq_u32 %[cnt], 0\n\t"
        "s_cbranch_scc1 .LEXIT%=\n\t"
        // ---- P3 (R21 verbatim): y4 v116-119, p v100-115 ----
        "v_mul_f32 v100, v36, v116\n\t"
        "v_mul_f32 v101, v40, v116\n\t"
        "v_mul_f32 v102, v44, v116\n\t"
        "v_mul_f32 v103, v48, v116\n\t"
        "v_mul_f32 v104, v52, v116\n\t"
        "v_mul_f32 v105, v56, v116\n\t"
        "v_mul_f32 v106, v60, v116\n\t"
        "v_mul_f32 v107, v64, v116\n\t"
        "v_mul_f32 v108, v68, v116\n\t"
        "v_mul_f32 v109, v72, v116\n\t"
        "v_mul_f32 v110, v76, v116\n\t"
        "v_mul_f32 v111, v80, v116\n\t"
        "v_mul_f32 v112, v84, v116\n\t"
        "v_mul_f32 v113, v88, v116\n\t"
        "v_mul_f32 v114, v92, v116\n\t"
        "v_mul_f32 v115, v96, v116\n\t"
        "v_fmac_f32 v100, v37, v117\n\t"
        "v_fmac_f32 v101, v41, v117\n\t"
        "v_fmac_f32 v102, v45, v117\n\t"
        "v_fmac_f32 v103, v49, v117\n\t"
        "v_fmac_f32 v104, v53, v117\n\t"
        "v_fmac_f32 v105, v57, v117\n\t"
        "v_fmac_f32 v106, v61, v117\n\t"
        "v_fmac_f32 v107, v65, v117\n\t"
        "v_fmac_f32 v108, v69, v117\n\t"
        "v_fmac_f32 v109, v73, v117\n\t"
        "v_fmac_f32 v110, v77, v117\n\t"
        "v_fmac_f32 v111, v81, v117\n\t"
        "v_fmac_f32 v112, v85, v117\n\t"
        "v_fmac_f32 v113, v89, v117\n\t"
        "v_fmac_f32 v114, v93, v117\n\t"
        "v_fmac_f32 v115, v97, v117\n\t"
        "v_fmac_f32 v100, v38, v118\n\t"
        "v_fmac_f32 v101, v42, v118\n\t"
        "v_fmac_f32 v102, v46, v118\n\t"
        "v_fmac_f32 v103, v50, v118\n\t"
        "v_fmac_f32 v104, v54, v118\n\t"
        "v_fmac_f32 v105, v58, v118\n\t"
        "v_fmac_f32 v106, v62, v118\n\t"
        "v_fmac_f32 v107, v66, v118\n\t"
        "v_fmac_f32 v108, v70, v118\n\t"
        "v_fmac_f32 v109, v74, v118\n\t"
        "v_fmac_f32 v110, v78, v118\n\t"
        "v_fmac_f32 v111, v82, v118\n\t"
        "v_fmac_f32 v112, v86, v118\n\t"
        "v_fmac_f32 v113, v90, v118\n\t"
        "v_fmac_f32 v114, v94, v118\n\t"
        "v_fmac_f32 v115, v98, v118\n\t"
        "v_fmac_f32 v100, v39, v119\n\t"
        "v_fmac_f32 v101, v43, v119\n\t"
        "v_fmac_f32 v102, v47, v119\n\t"
        "v_fmac_f32 v103, v51, v119\n\t"
        "v_fmac_f32 v104, v55, v119\n\t"
        "v_fmac_f32 v105, v59, v119\n\t"
        "v_fmac_f32 v106, v63, v119\n\t"
        "v_fmac_f32 v107, v67, v119\n\t"
        "v_fmac_f32 v108, v71, v119\n\t"
        "v_fmac_f32 v109, v75, v119\n\t"
        "v_fmac_f32 v110, v79, v119\n\t"
        "v_fmac_f32 v111, v83, v119\n\t"
        "v_fmac_f32 v112, v87, v119\n\t"
        "v_fmac_f32 v113, v91, v119\n\t"
        "v_fmac_f32 v114, v95, v119\n\t"
        "v_fmac_f32 v115, v99, v119\n\t"
        // ---- reduce (R22 verbatim): swap32 x8, swap16 x4, xor8, xor4, bf ----
        "s_nop 1\n\t"
        "v_permlane32_swap_b32 v100, v108\n\t"
        "v_permlane32_swap_b32 v101, v109\n\t"
        "v_permlane32_swap_b32 v102, v110\n\t"
        "v_permlane32_swap_b32 v103, v111\n\t"
        "v_permlane32_swap_b32 v104, v112\n\t"
        "v_permlane32_swap_b32 v105, v113\n\t"
        "v_permlane32_swap_b32 v106, v114\n\t"
        "v_permlane32_swap_b32 v107, v115\n\t"
        "v_add_f32 v100, v100, v108\n\t"
        "v_add_f32 v101, v101, v109\n\t"
        "v_add_f32 v102, v102, v110\n\t"
        "v_add_f32 v103, v103, v111\n\t"
        "v_add_f32 v104, v104, v112\n\t"
        "v_add_f32 v105, v105, v113\n\t"
        "v_add_f32 v106, v106, v114\n\t"
        "v_add_f32 v107, v107, v115\n\t"
        "v_permlane16_swap_b32 v100, v104\n\t"
        "v_permlane16_swap_b32 v101, v105\n\t"
        "v_permlane16_swap_b32 v102, v106\n\t"
        "v_permlane16_swap_b32 v103, v107\n\t"
        "v_add_f32 v100, v100, v104\n\t"
        "v_add_f32 v101, v101, v105\n\t"
        "v_add_f32 v102, v102, v106\n\t"
        "v_add_f32 v103, v103, v107\n\t"
        "v_cndmask_b32 v120, v100, v102, %[mb3]\n\t"
        "v_cndmask_b32 v121, v102, v100, %[mb3]\n\t"
        "v_cndmask_b32 v122, v101, v103, %[mb3]\n\t"
        "v_cndmask_b32 v123, v103, v101, %[mb3]\n\t"
        "s_nop 1\n\t"
        "v_mov_b32_dpp v124, v121 row_ror:8 row_mask:0xf bank_mask:0xf\n\t"
        "v_mov_b32_dpp v125, v123 row_ror:8 row_mask:0xf bank_mask:0xf\n\t"
        "v_add_f32 v100, v120, v124\n\t"
        "v_add_f32 v101, v122, v125\n\t"
        "v_cndmask_b32 v120, v100, v101, %[mb2]\n\t"
        "v_cndmask_b32 v121, v101, v100, %[mb2]\n\t"
        "ds_swizzle_b32 v121, v121 offset:0x101F\n\t"
        "s_waitcnt lgkmcnt(0)\n\t"
        "v_add_f32 v100, v120, v121\n\t"
        "s_nop 1\n\t"
        "v_mov_b32_dpp v121, v100 quad_perm:[2,3,0,1] row_mask:0xf bank_mask:0xf\n\t"
        "v_add_f32 v100, v100, v121\n\t"
        "s_nop 1\n\t"
        "v_mov_b32_dpp v121, v100 quad_perm:[1,0,3,2] row_mask:0xf bank_mask:0xf\n\t"
        "v_add_f32 v100, v100, v121\n\t"
        // ---- lambda update + wave-local publish ----
        "v_fmac_f32 %[lam], %[step], v100\n\t"
        "v_add_f32 %[lam], %[sb], %[lam]\n\t"
        "v_max_f32 %[lam], 0, %[lam]\n\t"
        "ds_write_b32 %[lamw], %[lam]\n\t"
        "s_sub_u32 %[cnt], %[cnt], 1\n\t"
        "s_branch .LTOP%=\n\t"
        ".LEXIT%=:\n\t"
        // wave 0 stores its 4 cols (y4 = v116-119 covers all 256 cols)
        "s_cmp_lg_u32 s78, 0\n\t"
        "s_cbranch_scc1 .LSKIP%=\n\t"
        "global_store_dwordx4 %[outa], v[116:119], off\n\t"
        ".LSKIP%=:\n\t"
        "s_waitcnt vmcnt(0)\n\t"
        : [lam] "+v"(lam), [cnt] "+s"(cnt), [zpw] "+v"(zpw), [zprd] "+v"(zprd)
        : [a0] "v"(a0), [a4] "v"(a4), [a8] "v"(a8), [a12] "v"(a12),
          [lamrd] "v"(lamrd), [lamw] "v"(lamw), [outa] "v"(outa),
          [c0] "v"(c0), [c1] "v"(c1), [c2] "v"(c2), [c3] "v"(c3),
          [sb] "v"(sbv), [wvv] "v"(wvv),
          [step] "s"(0.05f), [l2e] "s"(1.4426950408889634f),
          [mb3] "s"(0xFF00FF00FF00FF00ull), [mb2] "s"(0xF0F0F0F0F0F0F0F0ull)
        : "memory", "scc", "s78",
          "v36","v37","v38","v39","v40","v41","v42","v43","v44","v45",
          "v46","v47","v48","v49","v50","v51","v52","v53","v54","v55",
          "v56","v57","v58","v59","v60","v61","v62","v63","v64","v65",
          "v66","v67","v68","v69","v70","v71","v72","v73","v74","v75",
          "v76","v77","v78","v79","v80","v81","v82","v83","v84","v85",
          "v86","v87","v88","v89","v90","v91","v92","v93","v94","v95",
          "v96","v97","v98","v99","v100","v101","v102","v103","v104",
          "v105","v106","v107","v108","v109","v110","v111","v112","v113",
          "v114","v115","v116","v117","v118","v119","v120","v121","v122",
          "v123","v124","v125","v126","v127");

    if (tid == 0) out[(size_t)BB * NN + bi] = 0.0f;  // status[bi] = int32 0
}

extern "C" void kernel_launch(void* const* d_in, const int* in_sizes, int n_in,
                              void* d_out, int out_size, void* d_ws, size_t ws_size,
                              hipStream_t stream) {
    const float* A  = (const float*)d_in[0];  // [2048,128,256]
    const float* Bv = (const float*)d_in[1];  // [2048,128]
    const float* C  = (const float*)d_in[2];  // [2048,256]
    float* out = (float*)d_out;               // y [2048,256] f32 ++ status [2048]

    cvx_dual_ascent<<<dim3(BB), dim3(512), 0, stream>>>(A, Bv, C, out);
}